// Round 14
// baseline (29.040 us; speedup 1.0000x reference)
//
#include <hip/hip_runtime.h>
#include <math.h>

#define NM 1024
#define NS 256
#define NK 1025
#define CS 4    // steps per chunk
#define NC 64   // chunks per sequence = lanes per wave

struct Q4 { float x, y, z, w; };

__device__ __forceinline__ Q4 qmul(const Q4 a, const Q4 b) {
    Q4 o;
    o.x = a.w*b.x + a.x*b.w + a.y*b.z - a.z*b.y;
    o.y = a.w*b.y - a.x*b.z + a.y*b.w + a.z*b.x;
    o.z = a.w*b.z + a.x*b.y - a.y*b.x + a.z*b.w;
    o.w = a.w*b.w - a.x*b.x - a.y*b.y - a.z*b.z;
    return o;
}

__device__ __forceinline__ void q2m(const Q4 q, float* R) {
    float x = q.x, y = q.y, z = q.z, w = q.w;
    R[0] = 1.f - 2.f*(y*y + z*z); R[1] = 2.f*(x*y - z*w);       R[2] = 2.f*(x*z + y*w);
    R[3] = 2.f*(x*y + z*w);       R[4] = 1.f - 2.f*(x*x + z*z); R[5] = 2.f*(y*z - x*w);
    R[6] = 2.f*(x*z - y*w);       R[7] = 2.f*(y*z + x*w);       R[8] = 1.f - 2.f*(x*x + y*y);
}

__device__ __forceinline__ void m3mul(float* o, const float* X, const float* Y) {
    #pragma unroll
    for (int r = 0; r < 3; ++r)
        #pragma unroll
        for (int c = 0; c < 3; ++c)
            o[r*3+c] = X[r*3+0]*Y[c] + X[r*3+1]*Y[3+c] + X[r*3+2]*Y[6+c];
}

__device__ __forceinline__ void m3v(float* o, const float* X, const float* v) {
    o[0] = X[0]*v[0] + X[1]*v[1] + X[2]*v[2];
    o[1] = X[3]*v[0] + X[4]*v[1] + X[5]*v[2];
    o[2] = X[6]*v[0] + X[7]*v[1] + X[8]*v[2];
}

__device__ __forceinline__ void skmul(float* o, float x, float y, float z, const float* M) {
    #pragma unroll
    for (int c = 0; c < 3; ++c) {
        float m0 = M[c], m1 = M[3+c], m2 = M[6+c];
        o[c]   = -z*m1 + y*m2;
        o[3+c] =  z*m0 - x*m2;
        o[6+c] = -y*m0 + x*m1;
    }
}

__device__ __forceinline__ void crossv(float* o, float x, float y, float z, const float* v) {
    o[0] = -z*v[1] + y*v[2];
    o[1] =  z*v[0] - x*v[2];
    o[2] = -y*v[0] + x*v[1];
}

__device__ __forceinline__ void ld12(float* dst, const float4* src) {
    float4 t0 = src[0], t1 = src[1], t2 = src[2];
    dst[0]=t0.x; dst[1]=t0.y; dst[2] =t0.z; dst[3] =t0.w;
    dst[4]=t1.x; dst[5]=t1.y; dst[6] =t1.z; dst[7] =t1.w;
    dst[8]=t2.x; dst[9]=t2.y; dst[10]=t2.z; dst[11]=t2.w;
}

// ------------------------------------------------------------------
// Single fused kernel, NORMAL launch (no cooperative): 256 blocks x
// 256 threads. Phase 1 = R13-verified wave-per-sequence scan (4 seqs
// per block). Then the rocPRIM-style "last block" pattern: each block
// fences + atomicAdds a ticket; the block drawing ticket 255 runs
// phase 2 (R12-verified 256-thread re-blocked form). Deterministic:
// whichever block is last reads identical ws data -> bitwise-identical
// output. Counter is zeroed by hipMemsetAsync before each launch.
// ------------------------------------------------------------------
__global__ __launch_bounds__(256, 2) void imu_fused(
    const float* __restrict__ acc, const float* __restrict__ gyro,
    const float* __restrict__ dt, const float* __restrict__ bias_a,
    const float* __restrict__ bias_w, float* __restrict__ ws,
    const float* __restrict__ g, const float* __restrict__ init_rot,
    const float* __restrict__ init_pos, const float* __restrict__ init_vel,
    const float* __restrict__ gt_rot, const float* __restrict__ gt_pos,
    const float* __restrict__ gt_vel, float* __restrict__ out,
    unsigned int* __restrict__ counter)
{
    __shared__ float4 srot[NK];      // phase-2 only (last block)
    __shared__ float  svel[NK][3];
    __shared__ float  spos[NK][3];
    __shared__ float4 qtot[4];
    __shared__ float  vtot[4][3];
    __shared__ float  ptot[4][3];
    __shared__ unsigned int s_ticket;

    float* g_gamma = ws;            // NM*4
    float* g_beta  = ws + 4*NM;     // NM*3
    float* g_alpha = ws + 7*NM;     // NM*3
    float* g_kf    = ws + 10*NM;    // NM

    // ================= PHASE 1 (R13 verbatim, predicated store) ==========
    {
        const int lane = threadIdx.x & 63;
        const int m    = blockIdx.x * 4 + (threadIdx.x >> 6);
        const int c    = lane;

        float av[12], gv[12], bav[12], bwv[12], dtv[4];
        ld12(av,  (const float4*)(acc    + (size_t)m*NS*3) + c*3);
        ld12(gv,  (const float4*)(gyro   + (size_t)m*NS*3) + c*3);
        ld12(bav, (const float4*)(bias_a + (size_t)m*NS*3) + c*3);
        ld12(bwv, (const float4*)(bias_w + (size_t)m*NS*3) + c*3);
        {
            float4 t = ((const float4*)(dt + (size_t)m*NS))[c];
            dtv[0]=t.x; dtv[1]=t.y; dtv[2]=t.z; dtv[3]=t.w;
        }

        float ba0[3], bw0[3];
        ba0[0] = __shfl(bav[0], 0, 64); ba0[1] = __shfl(bav[1], 0, 64); ba0[2] = __shfl(bav[2], 0, 64);
        bw0[0] = __shfl(bwv[0], 0, 64); bw0[1] = __shfl(bwv[1], 0, 64); bw0[2] = __shfl(bwv[2], 0, 64);

        Q4 fq = {0.f, 0.f, 0.f, 1.f};
        float G[9] = {1.f,0.f,0.f, 0.f,1.f,0.f, 0.f,0.f,1.f};
        float T = 0.f;
        float u[3] = {0.f}, z[3] = {0.f};
        float A[9]  = {1.f,0.f,0.f, 0.f,1.f,0.f, 0.f,0.f,1.f};
        float Bmv[3] = {0.f};
        float M1v[3] = {0.f}, N[9] = {0.f}, nnv[3] = {0.f};
        float K1v[3] = {0.f}, K2a[9] = {0.f}, k2bv[3] = {0.f};

        #pragma unroll
        for (int j = 0; j < CS; ++j) {
            float d  = dtv[j];
            float ax = av[j*3+0], ay = av[j*3+1], az = av[j*3+2];
            float gx = gv[j*3+0], gy = gv[j*3+1], gz = gv[j*3+2];
            float abx = ax - bav[j*3+0], aby = ay - bav[j*3+1], abz = az - bav[j*3+2];
            float wbx = gx - bwv[j*3+0], wby = gy - bwv[j*3+1], wbz = gz - bwv[j*3+2];

            #pragma unroll
            for (int i = 0; i < 3; ++i) { K1v[i] += d*M1v[i]; k2bv[i] += d*nnv[i]; }
            #pragma unroll
            for (int i = 0; i < 9; ++i) K2a[i] += d*N[i];

            float ga0 = G[0]*ax + G[1]*ay + G[2]*az;
            float ga1 = G[3]*ax + G[4]*ay + G[5]*az;
            float ga2 = G[6]*ax + G[7]*ay + G[8]*az;
            float hd2 = 0.5f*d*d;
            z[0] += d*u[0] + hd2*ga0;
            z[1] += d*u[1] + hd2*ga1;
            z[2] += d*u[2] + hd2*ga2;
            u[0] += d*ga0; u[1] += d*ga1; u[2] += d*ga2;
            T += d;

            float phx = gx*d, phy = gy*d, phz = gz*d;
            float th2 = phx*phx + phy*phy + phz*phz;
            float k  = 0.5f - th2*(1.0f/48.0f);
            float ew = 1.0f - th2*0.125f;
            Q4 e = {phx*k, phy*k, phz*k, ew};
            fq = qmul(fq, e);
            q2m(fq, G);

            {
                float gb[3]; m3v(gb, G, ba0);
                M1v[0] += d*gb[0]; M1v[1] += d*gb[1]; M1v[2] += d*gb[2];
            }
            {
                float SA[9], GX[9];
                skmul(SA, abx, aby, abz, A);
                m3mul(GX, G, SA);
                #pragma unroll
                for (int i = 0; i < 9; ++i) N[i] += d*GX[i];
            }
            {
                float cb[3], gc[3];
                crossv(cb, abx, aby, abz, Bmv);
                m3v(gc, G, cb);
                nnv[0] += d*gc[0]; nnv[1] += d*gc[1]; nnv[2] += d*gc[2];
            }
            {
                float WA[9];
                skmul(WA, wbx, wby, wbz, A);
                #pragma unroll
                for (int i = 0; i < 9; ++i) A[i] -= d*WA[i];
            }
            {
                float cw[3];
                crossv(cw, wbx, wby, wbz, Bmv);
                Bmv[0] -= d*(cw[0] + bw0[0]);
                Bmv[1] -= d*(cw[1] + bw0[1]);
                Bmv[2] -= d*(cw[2] + bw0[2]);
            }
        }

        // fused scan: quat prefix (+T) and affine (A,b) prefix
        Q4 qi = fq;
        float Ti = T;
        float bvec[3] = {Bmv[0], Bmv[1], Bmv[2]};
        #pragma unroll
        for (int off = 1; off < 64; off <<= 1) {
            Q4 y;
            y.x = __shfl_up(qi.x, off, 64);
            y.y = __shfl_up(qi.y, off, 64);
            y.z = __shfl_up(qi.z, off, 64);
            y.w = __shfl_up(qi.w, off, 64);
            float yT = __shfl_up(Ti, off, 64);
            float yA[9], yb[3];
            #pragma unroll
            for (int i = 0; i < 9; ++i) yA[i] = __shfl_up(A[i], off, 64);
            yb[0] = __shfl_up(bvec[0], off, 64);
            yb[1] = __shfl_up(bvec[1], off, 64);
            yb[2] = __shfl_up(bvec[2], off, 64);
            if (lane >= off) {
                qi = qmul(y, qi);
                Ti += yT;
                float nA[9], nb[3];
                m3mul(nA, A, yA);
                m3v(nb, A, yb);
                #pragma unroll
                for (int i = 0; i < 9; ++i) A[i] = nA[i];
                bvec[0] = nb[0] + bvec[0];
                bvec[1] = nb[1] + bvec[1];
                bvec[2] = nb[2] + bvec[2];
            }
        }

        Q4 qf;
        qf.x = __shfl(qi.x, 63, 64);
        qf.y = __shfl(qi.y, 63, 64);
        qf.z = __shfl(qi.z, 63, 64);
        qf.w = __shfl(qi.w, 63, 64);
        Q4 qp;
        qp.x = __shfl_up(qi.x, 1, 64);
        qp.y = __shfl_up(qi.y, 1, 64);
        qp.z = __shfl_up(qi.z, 1, 64);
        qp.w = __shfl_up(qi.w, 1, 64);
        if (lane == 0) { qp.x = 0.f; qp.y = 0.f; qp.z = 0.f; qp.w = 1.f; }
        float R[9]; q2m(qp, R);

        float Tw = __shfl(Ti, 63, 64);
        float Tsuf = Tw - Ti;

        float Q2fv[3];
        Q2fv[0] = __shfl(bvec[0], 63, 64);
        Q2fv[1] = __shfl(bvec[1], 63, 64);
        Q2fv[2] = __shfl(bvec[2], 63, 64);
        float qv[3];
        qv[0] = __shfl_up(bvec[0], 1, 64);
        qv[1] = __shfl_up(bvec[1], 1, 64);
        qv[2] = __shfl_up(bvec[2], 1, 64);
        if (lane == 0) { qv[0] = 0.f; qv[1] = 0.f; qv[2] = 0.f; }

        float nq[3], kq[3];
        m3v(nq, N, qv);
        m3v(kq, K2a, qv);
        float t1[3] = { u[0] - M1v[0] - nq[0] - nnv[0],
                        u[1] - M1v[1] - nq[1] - nnv[1],
                        u[2] - M1v[2] - nq[2] - nnv[2] };
        float t2[3] = { z[0] - K1v[0] - kq[0] - k2bv[0],
                        z[1] - K1v[1] - kq[1] - k2bv[1],
                        z[2] - K1v[2] - kq[2] - k2bv[2] };
        float bc[3], ac[3];
        m3v(bc, R, t1);
        m3v(ac, R, t2);
        ac[0] += Tsuf*bc[0]; ac[1] += Tsuf*bc[1]; ac[2] += Tsuf*bc[2];

        #pragma unroll
        for (int off = 1; off < 64; off <<= 1) {
            #pragma unroll
            for (int i = 0; i < 3; ++i) {
                bc[i] += __shfl_xor(bc[i], off, 64);
                ac[i] += __shfl_xor(ac[i], off, 64);
            }
        }

        if (lane == 0) {
            float dthx = 0.5f*Q2fv[0], dthy = 0.5f*Q2fv[1], dthz = 0.5f*Q2fv[2];
            Q4 dq = {dthx, dthy, dthz, 1.0f};
            Q4 gamma = qmul(qf, dq);
            g_gamma[m*4+0] = gamma.x; g_gamma[m*4+1] = gamma.y;
            g_gamma[m*4+2] = gamma.z; g_gamma[m*4+3] = gamma.w;
            g_beta[m*3+0] = bc[0];  g_beta[m*3+1] = bc[1];  g_beta[m*3+2] = bc[2];
            g_alpha[m*3+0] = ac[0]; g_alpha[m*3+1] = ac[1]; g_alpha[m*3+2] = ac[2];
            g_kf[m] = Tw;
        }
    }

    // ================= last-block ticket =================
    __syncthreads();
    if (threadIdx.x == 0) {
        __threadfence();                       // release our ws writes
        s_ticket = atomicAdd(counter, 1u);     // device-scope
    }
    __syncthreads();
    if (s_ticket != (unsigned)(gridDim.x - 1)) return;
    __threadfence();                           // acquire all blocks' writes

    // ================= PHASE 2 (R12-verified 256-thread form) ============
    {
        const int tid  = threadIdx.x;   // 0..255
        const int lane = tid & 63;
        const int w    = tid >> 6;      // 0..3

        Q4 qinit = {init_rot[0], init_rot[1], init_rot[2], init_rot[3]};

        Q4 l0, l1, l2, l3;
        {
            const float4* gg = (const float4*)g_gamma;
            float4 a = gg[4*tid+0]; l0 = {a.x, a.y, a.z, a.w};
            float4 b = gg[4*tid+1]; l1 = qmul(l0, Q4{b.x, b.y, b.z, b.w});
            float4 cq = gg[4*tid+2]; l2 = qmul(l1, Q4{cq.x, cq.y, cq.z, cq.w});
            float4 dq = gg[4*tid+3]; l3 = qmul(l2, Q4{dq.x, dq.y, dq.z, dq.w});
        }
        Q4 inc = l3;
        #pragma unroll
        for (int off = 1; off < 64; off <<= 1) {
            Q4 y;
            y.x = __shfl_up(inc.x, off, 64);
            y.y = __shfl_up(inc.y, off, 64);
            y.z = __shfl_up(inc.z, off, 64);
            y.w = __shfl_up(inc.w, off, 64);
            if (lane >= off) inc = qmul(y, inc);
        }
        Q4 exc;
        exc.x = __shfl_up(inc.x, 1, 64);
        exc.y = __shfl_up(inc.y, 1, 64);
        exc.z = __shfl_up(inc.z, 1, 64);
        exc.w = __shfl_up(inc.w, 1, 64);
        if (lane == 0) { exc.x = 0.f; exc.y = 0.f; exc.z = 0.f; exc.w = 1.f; }
        if (lane == 63) qtot[w] = make_float4(inc.x, inc.y, inc.z, inc.w);
        __syncthreads();
        Q4 wpre = {0.f, 0.f, 0.f, 1.f};
        for (int j = 0; j < w; ++j) {
            float4 tq = qtot[j];
            wpre = qmul(wpre, Q4{tq.x, tq.y, tq.z, tq.w});
        }
        Q4 base = qmul(qmul(qinit, wpre), exc);
        Q4 r0 = base;
        Q4 r1 = qmul(base, l0);
        Q4 r2 = qmul(base, l1);
        Q4 r3 = qmul(base, l2);
        Q4 r4 = qmul(base, l3);
        srot[4*tid+1] = make_float4(r1.x, r1.y, r1.z, r1.w);
        srot[4*tid+2] = make_float4(r2.x, r2.y, r2.z, r2.w);
        srot[4*tid+3] = make_float4(r3.x, r3.y, r3.z, r3.w);
        srot[4*tid+4] = make_float4(r4.x, r4.y, r4.z, r4.w);
        if (tid == 0) srot[0] = make_float4(qinit.x, qinit.y, qinit.z, qinit.w);

        const float gx = g[0], gy = g[1], gz = g[2];
        const float iv0 = init_vel[0], iv1 = init_vel[1], iv2 = init_vel[2];
        const float ip0 = init_pos[0], ip1 = init_pos[1], ip2 = init_pos[2];

        float4 kf4 = ((const float4*)g_kf)[tid];
        float kf[4] = {kf4.x, kf4.y, kf4.z, kf4.w};
        float be[4][3], al[4][3];
        {
            const float4* gb = (const float4*)g_beta;
            float4 x0 = gb[3*tid+0], x1 = gb[3*tid+1], x2 = gb[3*tid+2];
            be[0][0]=x0.x; be[0][1]=x0.y; be[0][2]=x0.z;
            be[1][0]=x0.w; be[1][1]=x1.x; be[1][2]=x1.y;
            be[2][0]=x1.z; be[2][1]=x1.w; be[2][2]=x2.x;
            be[3][0]=x2.y; be[3][1]=x2.z; be[3][2]=x2.w;
            const float4* ga = (const float4*)g_alpha;
            float4 y0 = ga[3*tid+0], y1 = ga[3*tid+1], y2 = ga[3*tid+2];
            al[0][0]=y0.x; al[0][1]=y0.y; al[0][2]=y0.z;
            al[1][0]=y0.w; al[1][1]=y1.x; al[1][2]=y1.y;
            al[2][0]=y1.z; al[2][1]=y1.w; al[2][2]=y2.x;
            al[3][0]=y2.y; al[3][1]=y2.z; al[3][2]=y2.w;
        }
        Q4 rr[4] = {r0, r1, r2, r3};

        float dv[4][3], sv[4][3];
        #pragma unroll
        for (int i = 0; i < 4; ++i) {
            float Rw[9]; q2m(rr[i], Rw);
            dv[i][0] = -gx*kf[i] + Rw[0]*be[i][0] + Rw[1]*be[i][1] + Rw[2]*be[i][2];
            dv[i][1] = -gy*kf[i] + Rw[3]*be[i][0] + Rw[4]*be[i][1] + Rw[5]*be[i][2];
            dv[i][2] = -gz*kf[i] + Rw[6]*be[i][0] + Rw[7]*be[i][1] + Rw[8]*be[i][2];
            #pragma unroll
            for (int k = 0; k < 3; ++k)
                sv[i][k] = (i == 0) ? dv[0][k] : sv[i-1][k] + dv[i][k];
        }
        float a0s = sv[3][0], a1s = sv[3][1], a2s = sv[3][2];
        #pragma unroll
        for (int off = 1; off < 64; off <<= 1) {
            float y0 = __shfl_up(a0s, off, 64);
            float y1 = __shfl_up(a1s, off, 64);
            float y2 = __shfl_up(a2s, off, 64);
            if (lane >= off) { a0s += y0; a1s += y1; a2s += y2; }
        }
        float e0 = __shfl_up(a0s, 1, 64);
        float e1 = __shfl_up(a1s, 1, 64);
        float e2 = __shfl_up(a2s, 1, 64);
        if (lane == 0) { e0 = 0.f; e1 = 0.f; e2 = 0.f; }
        if (lane == 63) { vtot[w][0] = a0s; vtot[w][1] = a1s; vtot[w][2] = a2s; }
        __syncthreads();
        {
            float p0 = 0.f, p1 = 0.f, p2 = 0.f;
            for (int j = 0; j < w; ++j) { p0 += vtot[j][0]; p1 += vtot[j][1]; p2 += vtot[j][2]; }
            e0 += p0; e1 += p1; e2 += p2;
        }
        float velm[4][3];
        #pragma unroll
        for (int i = 0; i < 4; ++i) {
            velm[i][0] = iv0 + e0 + ((i == 0) ? 0.f : sv[i-1][0]);
            velm[i][1] = iv1 + e1 + ((i == 0) ? 0.f : sv[i-1][1]);
            velm[i][2] = iv2 + e2 + ((i == 0) ? 0.f : sv[i-1][2]);
            svel[4*tid+i+1][0] = iv0 + e0 + sv[i][0];
            svel[4*tid+i+1][1] = iv1 + e1 + sv[i][1];
            svel[4*tid+i+1][2] = iv2 + e2 + sv[i][2];
        }
        if (tid == 0) { svel[0][0] = iv0; svel[0][1] = iv1; svel[0][2] = iv2; }

        float dp[4][3], sp[4][3];
        #pragma unroll
        for (int i = 0; i < 4; ++i) {
            float Rw[9]; q2m(rr[i], Rw);
            float kk = kf[i], hk = 0.5f*kk*kk;
            dp[i][0] = velm[i][0]*kk - gx*hk + Rw[0]*al[i][0] + Rw[1]*al[i][1] + Rw[2]*al[i][2];
            dp[i][1] = velm[i][1]*kk - gy*hk + Rw[3]*al[i][0] + Rw[4]*al[i][1] + Rw[5]*al[i][2];
            dp[i][2] = velm[i][2]*kk - gz*hk + Rw[6]*al[i][0] + Rw[7]*al[i][1] + Rw[8]*al[i][2];
            #pragma unroll
            for (int k = 0; k < 3; ++k)
                sp[i][k] = (i == 0) ? dp[0][k] : sp[i-1][k] + dp[i][k];
        }
        float b0s = sp[3][0], b1s = sp[3][1], b2s = sp[3][2];
        #pragma unroll
        for (int off = 1; off < 64; off <<= 1) {
            float y0 = __shfl_up(b0s, off, 64);
            float y1 = __shfl_up(b1s, off, 64);
            float y2 = __shfl_up(b2s, off, 64);
            if (lane >= off) { b0s += y0; b1s += y1; b2s += y2; }
        }
        float f0 = __shfl_up(b0s, 1, 64);
        float f1 = __shfl_up(b1s, 1, 64);
        float f2 = __shfl_up(b2s, 1, 64);
        if (lane == 0) { f0 = 0.f; f1 = 0.f; f2 = 0.f; }
        if (lane == 63) { ptot[w][0] = b0s; ptot[w][1] = b1s; ptot[w][2] = b2s; }
        __syncthreads();
        {
            float p0 = 0.f, p1 = 0.f, p2 = 0.f;
            for (int j = 0; j < w; ++j) { p0 += ptot[j][0]; p1 += ptot[j][1]; p2 += ptot[j][2]; }
            f0 += p0; f1 += p1; f2 += p2;
        }
        #pragma unroll
        for (int i = 0; i < 4; ++i) {
            spos[4*tid+i+1][0] = ip0 + f0 + sp[i][0];
            spos[4*tid+i+1][1] = ip1 + f1 + sp[i][1];
            spos[4*tid+i+1][2] = ip2 + f2 + sp[i][2];
        }
        if (tid == 0) { spos[0][0] = ip0; spos[0][1] = ip1; spos[0][2] = ip2; }
        __syncthreads();

        for (int k = tid; k < NK; k += 256) {
            float4 rv = srot[k];
            Q4 rk = {rv.x, rv.y, rv.z, rv.w};
            Q4 gc = {-gt_rot[k*4+0], -gt_rot[k*4+1], -gt_rot[k*4+2], gt_rot[k*4+3]};
            Q4 e = qmul(gc, rk);
            float n2 = e.x*e.x + e.y*e.y + e.z*e.z;
            float n = sqrtf(n2);
            float theta = 2.f*atan2f(n, e.w);
            float scale;
            if (n < 1e-6f) {
                float wd = (fabsf(e.w) < 1e-6f) ? 1.f : e.w;
                scale = 2.f/wd;
            } else {
                scale = theta/n;
            }
            out[k*3+0] = e.x*scale;
            out[k*3+1] = e.y*scale;
            out[k*3+2] = e.z*scale;

            float d0 = gt_pos[k*3+0] - spos[k][0];
            float d1 = gt_pos[k*3+1] - spos[k][1];
            float d2 = gt_pos[k*3+2] - spos[k][2];
            out[(NK+k)*3+0] = d0*d0;
            out[(NK+k)*3+1] = d1*d1;
            out[(NK+k)*3+2] = d2*d2;

            float v0 = gt_vel[k*3+0] - svel[k][0];
            float v1 = gt_vel[k*3+1] - svel[k][1];
            float v2 = gt_vel[k*3+2] - svel[k][2];
            out[(2*NK+k)*3+0] = v0*v0;
            out[(2*NK+k)*3+1] = v1*v1;
            out[(2*NK+k)*3+2] = v2*v2;
        }
    }
}

extern "C" void kernel_launch(void* const* d_in, const int* in_sizes, int n_in,
                              void* d_out, int out_size, void* d_ws, size_t ws_size,
                              hipStream_t stream) {
    const float* acc      = (const float*)d_in[0];
    const float* gyro     = (const float*)d_in[1];
    const float* dt       = (const float*)d_in[2];
    const float* bias_a   = (const float*)d_in[3];
    const float* bias_w   = (const float*)d_in[4];
    const float* g        = (const float*)d_in[5];
    const float* init_rot = (const float*)d_in[6];
    const float* init_pos = (const float*)d_in[7];
    const float* init_vel = (const float*)d_in[8];
    const float* gt_rot   = (const float*)d_in[9];
    const float* gt_pos   = (const float*)d_in[10];
    const float* gt_vel   = (const float*)d_in[11];
    float* ws  = (float*)d_ws;
    float* out = (float*)d_out;

    // ticket counter lives just past the 11*NM-float ws region
    unsigned int* counter = (unsigned int*)((char*)d_ws + 11*NM*sizeof(float));
    hipMemsetAsync(counter, 0, sizeof(unsigned int), stream);

    imu_fused<<<NM/4, 256, 0, stream>>>(acc, gyro, dt, bias_a, bias_w, ws,
                                        g, init_rot, init_pos, init_vel,
                                        gt_rot, gt_pos, gt_vel, out, counter);
}

// Round 15
// 18.744 us; speedup vs baseline: 1.5493x; 1.5493x over previous
//
#include <hip/hip_runtime.h>
#include <math.h>

#define NM 1024
#define NS 256
#define NK 1025
#define CS 4    // steps per chunk
#define NC 64   // chunks per sequence = lanes per wave

struct Q4 { float x, y, z, w; };

__device__ __forceinline__ Q4 qmul(const Q4 a, const Q4 b) {
    Q4 o;
    o.x = a.w*b.x + a.x*b.w + a.y*b.z - a.z*b.y;
    o.y = a.w*b.y - a.x*b.z + a.y*b.w + a.z*b.x;
    o.z = a.w*b.z + a.x*b.y - a.y*b.x + a.z*b.w;
    o.w = a.w*b.w - a.x*b.x - a.y*b.y - a.z*b.z;
    return o;
}

__device__ __forceinline__ void q2m(const Q4 q, float* R) {
    float x = q.x, y = q.y, z = q.z, w = q.w;
    R[0] = 1.f - 2.f*(y*y + z*z); R[1] = 2.f*(x*y - z*w);       R[2] = 2.f*(x*z + y*w);
    R[3] = 2.f*(x*y + z*w);       R[4] = 1.f - 2.f*(x*x + z*z); R[5] = 2.f*(y*z - x*w);
    R[6] = 2.f*(x*z - y*w);       R[7] = 2.f*(y*z + x*w);       R[8] = 1.f - 2.f*(x*x + y*y);
}

__device__ __forceinline__ void m3mul(float* o, const float* X, const float* Y) {
    #pragma unroll
    for (int r = 0; r < 3; ++r)
        #pragma unroll
        for (int c = 0; c < 3; ++c)
            o[r*3+c] = X[r*3+0]*Y[c] + X[r*3+1]*Y[3+c] + X[r*3+2]*Y[6+c];
}

__device__ __forceinline__ void m3v(float* o, const float* X, const float* v) {
    o[0] = X[0]*v[0] + X[1]*v[1] + X[2]*v[2];
    o[1] = X[3]*v[0] + X[4]*v[1] + X[5]*v[2];
    o[2] = X[6]*v[0] + X[7]*v[1] + X[8]*v[2];
}

__device__ __forceinline__ void skmul(float* o, float x, float y, float z, const float* M) {
    #pragma unroll
    for (int c = 0; c < 3; ++c) {
        float m0 = M[c], m1 = M[3+c], m2 = M[6+c];
        o[c]   = -z*m1 + y*m2;
        o[3+c] =  z*m0 - x*m2;
        o[6+c] = -y*m0 + x*m1;
    }
}

__device__ __forceinline__ void crossv(float* o, float x, float y, float z, const float* v) {
    o[0] = -z*v[1] + y*v[2];
    o[1] =  z*v[0] - x*v[2];
    o[2] = -y*v[0] + x*v[1];
}

__device__ __forceinline__ void ld12(float* dst, const float4* src) {
    float4 t0 = src[0], t1 = src[1], t2 = src[2];
    dst[0]=t0.x; dst[1]=t0.y; dst[2] =t0.z; dst[3] =t0.w;
    dst[4]=t1.x; dst[5]=t1.y; dst[6] =t1.z; dst[7] =t1.w;
    dst[8]=t2.x; dst[9]=t2.y; dst[10]=t2.z; dst[11]=t2.w;
}

// ------------------------------------------------------------------
// Phase 1 (R13-verified): wave per sequence, lane = chunk (CS=4),
// bias-contracted leaf fields + ONE fused 6-round scan (quat+T+affine)
// + 6-round butterfly. No LDS, no barriers.
// ------------------------------------------------------------------
__global__ __launch_bounds__(256, 2) void imu_phase1(
    const float* __restrict__ acc, const float* __restrict__ gyro,
    const float* __restrict__ dt, const float* __restrict__ bias_a,
    const float* __restrict__ bias_w, float* __restrict__ ws)
{
    const int lane = threadIdx.x & 63;
    const int m    = blockIdx.x * 4 + (threadIdx.x >> 6);
    const int c    = lane;

    float av[12], gv[12], bav[12], bwv[12], dtv[4];
    ld12(av,  (const float4*)(acc    + (size_t)m*NS*3) + c*3);
    ld12(gv,  (const float4*)(gyro   + (size_t)m*NS*3) + c*3);
    ld12(bav, (const float4*)(bias_a + (size_t)m*NS*3) + c*3);
    ld12(bwv, (const float4*)(bias_w + (size_t)m*NS*3) + c*3);
    {
        float4 t = ((const float4*)(dt + (size_t)m*NS))[c];
        dtv[0]=t.x; dtv[1]=t.y; dtv[2]=t.z; dtv[3]=t.w;
    }

    float ba0[3], bw0[3];
    ba0[0] = __shfl(bav[0], 0, 64); ba0[1] = __shfl(bav[1], 0, 64); ba0[2] = __shfl(bav[2], 0, 64);
    bw0[0] = __shfl(bwv[0], 0, 64); bw0[1] = __shfl(bwv[1], 0, 64); bw0[2] = __shfl(bwv[2], 0, 64);

    Q4 fq = {0.f, 0.f, 0.f, 1.f};
    float G[9] = {1.f,0.f,0.f, 0.f,1.f,0.f, 0.f,0.f,1.f};
    float T = 0.f;
    float u[3] = {0.f}, z[3] = {0.f};
    float A[9]  = {1.f,0.f,0.f, 0.f,1.f,0.f, 0.f,0.f,1.f};
    float Bmv[3] = {0.f};
    float M1v[3] = {0.f}, N[9] = {0.f}, nnv[3] = {0.f};
    float K1v[3] = {0.f}, K2a[9] = {0.f}, k2bv[3] = {0.f};

    #pragma unroll
    for (int j = 0; j < CS; ++j) {
        float d  = dtv[j];
        float ax = av[j*3+0], ay = av[j*3+1], az = av[j*3+2];
        float gx = gv[j*3+0], gy = gv[j*3+1], gz = gv[j*3+2];
        float abx = ax - bav[j*3+0], aby = ay - bav[j*3+1], abz = az - bav[j*3+2];
        float wbx = gx - bwv[j*3+0], wby = gy - bwv[j*3+1], wbz = gz - bwv[j*3+2];

        #pragma unroll
        for (int i = 0; i < 3; ++i) { K1v[i] += d*M1v[i]; k2bv[i] += d*nnv[i]; }
        #pragma unroll
        for (int i = 0; i < 9; ++i) K2a[i] += d*N[i];

        float ga0 = G[0]*ax + G[1]*ay + G[2]*az;
        float ga1 = G[3]*ax + G[4]*ay + G[5]*az;
        float ga2 = G[6]*ax + G[7]*ay + G[8]*az;
        float hd2 = 0.5f*d*d;
        z[0] += d*u[0] + hd2*ga0;
        z[1] += d*u[1] + hd2*ga1;
        z[2] += d*u[2] + hd2*ga2;
        u[0] += d*ga0; u[1] += d*ga1; u[2] += d*ga2;
        T += d;

        float phx = gx*d, phy = gy*d, phz = gz*d;
        float th2 = phx*phx + phy*phy + phz*phz;
        float k  = 0.5f - th2*(1.0f/48.0f);
        float ew = 1.0f - th2*0.125f;
        Q4 e = {phx*k, phy*k, phz*k, ew};
        fq = qmul(fq, e);
        q2m(fq, G);

        {
            float gb[3]; m3v(gb, G, ba0);
            M1v[0] += d*gb[0]; M1v[1] += d*gb[1]; M1v[2] += d*gb[2];
        }
        {
            float SA[9], GX[9];
            skmul(SA, abx, aby, abz, A);
            m3mul(GX, G, SA);
            #pragma unroll
            for (int i = 0; i < 9; ++i) N[i] += d*GX[i];
        }
        {
            float cb[3], gc[3];
            crossv(cb, abx, aby, abz, Bmv);
            m3v(gc, G, cb);
            nnv[0] += d*gc[0]; nnv[1] += d*gc[1]; nnv[2] += d*gc[2];
        }
        {
            float WA[9];
            skmul(WA, wbx, wby, wbz, A);
            #pragma unroll
            for (int i = 0; i < 9; ++i) A[i] -= d*WA[i];
        }
        {
            float cw[3];
            crossv(cw, wbx, wby, wbz, Bmv);
            Bmv[0] -= d*(cw[0] + bw0[0]);
            Bmv[1] -= d*(cw[1] + bw0[1]);
            Bmv[2] -= d*(cw[2] + bw0[2]);
        }
    }

    // fused scan: quat prefix (+T) and affine (A,b) prefix
    Q4 qi = fq;
    float Ti = T;
    float bvec[3] = {Bmv[0], Bmv[1], Bmv[2]};
    #pragma unroll
    for (int off = 1; off < 64; off <<= 1) {
        Q4 y;
        y.x = __shfl_up(qi.x, off, 64);
        y.y = __shfl_up(qi.y, off, 64);
        y.z = __shfl_up(qi.z, off, 64);
        y.w = __shfl_up(qi.w, off, 64);
        float yT = __shfl_up(Ti, off, 64);
        float yA[9], yb[3];
        #pragma unroll
        for (int i = 0; i < 9; ++i) yA[i] = __shfl_up(A[i], off, 64);
        yb[0] = __shfl_up(bvec[0], off, 64);
        yb[1] = __shfl_up(bvec[1], off, 64);
        yb[2] = __shfl_up(bvec[2], off, 64);
        if (lane >= off) {
            qi = qmul(y, qi);
            Ti += yT;
            float nA[9], nb[3];
            m3mul(nA, A, yA);
            m3v(nb, A, yb);
            #pragma unroll
            for (int i = 0; i < 9; ++i) A[i] = nA[i];
            bvec[0] = nb[0] + bvec[0];
            bvec[1] = nb[1] + bvec[1];
            bvec[2] = nb[2] + bvec[2];
        }
    }

    Q4 qf;
    qf.x = __shfl(qi.x, 63, 64);
    qf.y = __shfl(qi.y, 63, 64);
    qf.z = __shfl(qi.z, 63, 64);
    qf.w = __shfl(qi.w, 63, 64);
    Q4 qp;
    qp.x = __shfl_up(qi.x, 1, 64);
    qp.y = __shfl_up(qi.y, 1, 64);
    qp.z = __shfl_up(qi.z, 1, 64);
    qp.w = __shfl_up(qi.w, 1, 64);
    if (lane == 0) { qp.x = 0.f; qp.y = 0.f; qp.z = 0.f; qp.w = 1.f; }
    float R[9]; q2m(qp, R);

    float Tw = __shfl(Ti, 63, 64);
    float Tsuf = Tw - Ti;

    float Q2fv[3];
    Q2fv[0] = __shfl(bvec[0], 63, 64);
    Q2fv[1] = __shfl(bvec[1], 63, 64);
    Q2fv[2] = __shfl(bvec[2], 63, 64);
    float qv[3];
    qv[0] = __shfl_up(bvec[0], 1, 64);
    qv[1] = __shfl_up(bvec[1], 1, 64);
    qv[2] = __shfl_up(bvec[2], 1, 64);
    if (lane == 0) { qv[0] = 0.f; qv[1] = 0.f; qv[2] = 0.f; }

    float nq[3], kq[3];
    m3v(nq, N, qv);
    m3v(kq, K2a, qv);
    float t1[3] = { u[0] - M1v[0] - nq[0] - nnv[0],
                    u[1] - M1v[1] - nq[1] - nnv[1],
                    u[2] - M1v[2] - nq[2] - nnv[2] };
    float t2[3] = { z[0] - K1v[0] - kq[0] - k2bv[0],
                    z[1] - K1v[1] - kq[1] - k2bv[1],
                    z[2] - K1v[2] - kq[2] - k2bv[2] };
    float bc[3], ac[3];
    m3v(bc, R, t1);
    m3v(ac, R, t2);
    ac[0] += Tsuf*bc[0]; ac[1] += Tsuf*bc[1]; ac[2] += Tsuf*bc[2];

    #pragma unroll
    for (int off = 1; off < 64; off <<= 1) {
        #pragma unroll
        for (int i = 0; i < 3; ++i) {
            bc[i] += __shfl_xor(bc[i], off, 64);
            ac[i] += __shfl_xor(ac[i], off, 64);
        }
    }

    if (lane != 0) return;

    float dthx = 0.5f*Q2fv[0], dthy = 0.5f*Q2fv[1], dthz = 0.5f*Q2fv[2];
    Q4 dq = {dthx, dthy, dthz, 1.0f};
    Q4 gamma = qmul(qf, dq);

    float* g_gamma = ws;            // NM*4
    float* g_beta  = ws + 4*NM;     // NM*3
    float* g_alpha = ws + 7*NM;     // NM*3
    float* g_kf    = ws + 10*NM;    // NM
    g_gamma[m*4+0] = gamma.x; g_gamma[m*4+1] = gamma.y;
    g_gamma[m*4+2] = gamma.z; g_gamma[m*4+3] = gamma.w;
    g_beta[m*3+0] = bc[0];  g_beta[m*3+1] = bc[1];  g_beta[m*3+2] = bc[2];
    g_alpha[m*3+0] = ac[0]; g_alpha[m*3+1] = ac[1]; g_alpha[m*3+2] = ac[2];
    g_kf[m] = Tw;
}

// ------------------------------------------------------------------
// Phase 2 (R12/R14-verified 256-thread re-blocked form, standalone):
// 4 sequences per thread; wave shfl-scans + 4-wave LDS combine;
// only 3 barriers (vs ~10 in the 1024-thread version).
// ------------------------------------------------------------------
__global__ __launch_bounds__(256) void imu_phase2(
    const float* __restrict__ ws, const float* __restrict__ g,
    const float* __restrict__ init_rot, const float* __restrict__ init_pos,
    const float* __restrict__ init_vel, const float* __restrict__ gt_rot,
    const float* __restrict__ gt_pos, const float* __restrict__ gt_vel,
    float* __restrict__ out)
{
    __shared__ float4 srot[NK];
    __shared__ float  svel[NK][3];
    __shared__ float  spos[NK][3];
    __shared__ float4 qtot[4];
    __shared__ float  vtot[4][3];
    __shared__ float  ptot[4][3];

    const int tid  = threadIdx.x;   // 0..255
    const int lane = tid & 63;
    const int w    = tid >> 6;      // 0..3

    const float* g_gamma = ws;
    const float* g_beta  = ws + 4*NM;
    const float* g_alpha = ws + 7*NM;
    const float* g_kf    = ws + 10*NM;

    Q4 qinit = {init_rot[0], init_rot[1], init_rot[2], init_rot[3]};

    // ---- quat scan: local 4-compose + wave scan + cross-wave ----
    Q4 l0, l1, l2, l3;
    {
        const float4* gg = (const float4*)g_gamma;
        float4 a = gg[4*tid+0]; l0 = {a.x, a.y, a.z, a.w};
        float4 b = gg[4*tid+1]; l1 = qmul(l0, Q4{b.x, b.y, b.z, b.w});
        float4 cq = gg[4*tid+2]; l2 = qmul(l1, Q4{cq.x, cq.y, cq.z, cq.w});
        float4 dq = gg[4*tid+3]; l3 = qmul(l2, Q4{dq.x, dq.y, dq.z, dq.w});
    }
    Q4 inc = l3;
    #pragma unroll
    for (int off = 1; off < 64; off <<= 1) {
        Q4 y;
        y.x = __shfl_up(inc.x, off, 64);
        y.y = __shfl_up(inc.y, off, 64);
        y.z = __shfl_up(inc.z, off, 64);
        y.w = __shfl_up(inc.w, off, 64);
        if (lane >= off) inc = qmul(y, inc);
    }
    Q4 exc;
    exc.x = __shfl_up(inc.x, 1, 64);
    exc.y = __shfl_up(inc.y, 1, 64);
    exc.z = __shfl_up(inc.z, 1, 64);
    exc.w = __shfl_up(inc.w, 1, 64);
    if (lane == 0) { exc.x = 0.f; exc.y = 0.f; exc.z = 0.f; exc.w = 1.f; }
    if (lane == 63) qtot[w] = make_float4(inc.x, inc.y, inc.z, inc.w);
    __syncthreads();
    Q4 wpre = {0.f, 0.f, 0.f, 1.f};
    for (int j = 0; j < w; ++j) {
        float4 tq = qtot[j];
        wpre = qmul(wpre, Q4{tq.x, tq.y, tq.z, tq.w});
    }
    Q4 base = qmul(qmul(qinit, wpre), exc);   // rot at m = 4*tid (exclusive)
    Q4 r0 = base;
    Q4 r1 = qmul(base, l0);
    Q4 r2 = qmul(base, l1);
    Q4 r3 = qmul(base, l2);
    Q4 r4 = qmul(base, l3);
    srot[4*tid+1] = make_float4(r1.x, r1.y, r1.z, r1.w);
    srot[4*tid+2] = make_float4(r2.x, r2.y, r2.z, r2.w);
    srot[4*tid+3] = make_float4(r3.x, r3.y, r3.z, r3.w);
    srot[4*tid+4] = make_float4(r4.x, r4.y, r4.z, r4.w);
    if (tid == 0) srot[0] = make_float4(qinit.x, qinit.y, qinit.z, qinit.w);

    const float gx = g[0], gy = g[1], gz = g[2];
    const float iv0 = init_vel[0], iv1 = init_vel[1], iv2 = init_vel[2];
    const float ip0 = init_pos[0], ip1 = init_pos[1], ip2 = init_pos[2];

    float4 kf4 = ((const float4*)g_kf)[tid];
    float kf[4] = {kf4.x, kf4.y, kf4.z, kf4.w};
    float be[4][3], al[4][3];
    {
        const float4* gb = (const float4*)g_beta;
        float4 x0 = gb[3*tid+0], x1 = gb[3*tid+1], x2 = gb[3*tid+2];
        be[0][0]=x0.x; be[0][1]=x0.y; be[0][2]=x0.z;
        be[1][0]=x0.w; be[1][1]=x1.x; be[1][2]=x1.y;
        be[2][0]=x1.z; be[2][1]=x1.w; be[2][2]=x2.x;
        be[3][0]=x2.y; be[3][1]=x2.z; be[3][2]=x2.w;
        const float4* ga = (const float4*)g_alpha;
        float4 y0 = ga[3*tid+0], y1 = ga[3*tid+1], y2 = ga[3*tid+2];
        al[0][0]=y0.x; al[0][1]=y0.y; al[0][2]=y0.z;
        al[1][0]=y0.w; al[1][1]=y1.x; al[1][2]=y1.y;
        al[2][0]=y1.z; al[2][1]=y1.w; al[2][2]=y2.x;
        al[3][0]=y2.y; al[3][1]=y2.z; al[3][2]=y2.w;
    }
    Q4 rr[4] = {r0, r1, r2, r3};

    // ---- vel scan ----
    float dv[4][3], sv[4][3];
    #pragma unroll
    for (int i = 0; i < 4; ++i) {
        float Rw[9]; q2m(rr[i], Rw);
        dv[i][0] = -gx*kf[i] + Rw[0]*be[i][0] + Rw[1]*be[i][1] + Rw[2]*be[i][2];
        dv[i][1] = -gy*kf[i] + Rw[3]*be[i][0] + Rw[4]*be[i][1] + Rw[5]*be[i][2];
        dv[i][2] = -gz*kf[i] + Rw[6]*be[i][0] + Rw[7]*be[i][1] + Rw[8]*be[i][2];
        #pragma unroll
        for (int k = 0; k < 3; ++k)
            sv[i][k] = (i == 0) ? dv[0][k] : sv[i-1][k] + dv[i][k];
    }
    float a0s = sv[3][0], a1s = sv[3][1], a2s = sv[3][2];
    #pragma unroll
    for (int off = 1; off < 64; off <<= 1) {
        float y0 = __shfl_up(a0s, off, 64);
        float y1 = __shfl_up(a1s, off, 64);
        float y2 = __shfl_up(a2s, off, 64);
        if (lane >= off) { a0s += y0; a1s += y1; a2s += y2; }
    }
    float e0 = __shfl_up(a0s, 1, 64);
    float e1 = __shfl_up(a1s, 1, 64);
    float e2 = __shfl_up(a2s, 1, 64);
    if (lane == 0) { e0 = 0.f; e1 = 0.f; e2 = 0.f; }
    if (lane == 63) { vtot[w][0] = a0s; vtot[w][1] = a1s; vtot[w][2] = a2s; }
    __syncthreads();
    {
        float p0 = 0.f, p1 = 0.f, p2 = 0.f;
        for (int j = 0; j < w; ++j) { p0 += vtot[j][0]; p1 += vtot[j][1]; p2 += vtot[j][2]; }
        e0 += p0; e1 += p1; e2 += p2;
    }
    float velm[4][3];
    #pragma unroll
    for (int i = 0; i < 4; ++i) {
        velm[i][0] = iv0 + e0 + ((i == 0) ? 0.f : sv[i-1][0]);
        velm[i][1] = iv1 + e1 + ((i == 0) ? 0.f : sv[i-1][1]);
        velm[i][2] = iv2 + e2 + ((i == 0) ? 0.f : sv[i-1][2]);
        svel[4*tid+i+1][0] = iv0 + e0 + sv[i][0];
        svel[4*tid+i+1][1] = iv1 + e1 + sv[i][1];
        svel[4*tid+i+1][2] = iv2 + e2 + sv[i][2];
    }
    if (tid == 0) { svel[0][0] = iv0; svel[0][1] = iv1; svel[0][2] = iv2; }

    // ---- pos scan ----
    float dp[4][3], sp[4][3];
    #pragma unroll
    for (int i = 0; i < 4; ++i) {
        float Rw[9]; q2m(rr[i], Rw);
        float kk = kf[i], hk = 0.5f*kk*kk;
        dp[i][0] = velm[i][0]*kk - gx*hk + Rw[0]*al[i][0] + Rw[1]*al[i][1] + Rw[2]*al[i][2];
        dp[i][1] = velm[i][1]*kk - gy*hk + Rw[3]*al[i][0] + Rw[4]*al[i][1] + Rw[5]*al[i][2];
        dp[i][2] = velm[i][2]*kk - gz*hk + Rw[6]*al[i][0] + Rw[7]*al[i][1] + Rw[8]*al[i][2];
        #pragma unroll
        for (int k = 0; k < 3; ++k)
            sp[i][k] = (i == 0) ? dp[0][k] : sp[i-1][k] + dp[i][k];
    }
    float b0s = sp[3][0], b1s = sp[3][1], b2s = sp[3][2];
    #pragma unroll
    for (int off = 1; off < 64; off <<= 1) {
        float y0 = __shfl_up(b0s, off, 64);
        float y1 = __shfl_up(b1s, off, 64);
        float y2 = __shfl_up(b2s, off, 64);
        if (lane >= off) { b0s += y0; b1s += y1; b2s += y2; }
    }
    float f0 = __shfl_up(b0s, 1, 64);
    float f1 = __shfl_up(b1s, 1, 64);
    float f2 = __shfl_up(b2s, 1, 64);
    if (lane == 0) { f0 = 0.f; f1 = 0.f; f2 = 0.f; }
    if (lane == 63) { ptot[w][0] = b0s; ptot[w][1] = b1s; ptot[w][2] = b2s; }
    __syncthreads();
    {
        float p0 = 0.f, p1 = 0.f, p2 = 0.f;
        for (int j = 0; j < w; ++j) { p0 += ptot[j][0]; p1 += ptot[j][1]; p2 += ptot[j][2]; }
        f0 += p0; f1 += p1; f2 += p2;
    }
    #pragma unroll
    for (int i = 0; i < 4; ++i) {
        spos[4*tid+i+1][0] = ip0 + f0 + sp[i][0];
        spos[4*tid+i+1][1] = ip1 + f1 + sp[i][1];
        spos[4*tid+i+1][2] = ip2 + f2 + sp[i][2];
    }
    if (tid == 0) { spos[0][0] = ip0; spos[0][1] = ip1; spos[0][2] = ip2; }
    __syncthreads();

    // ---- epilogue over k in [0, NK) ----
    for (int k = tid; k < NK; k += 256) {
        float4 rv = srot[k];
        Q4 rk = {rv.x, rv.y, rv.z, rv.w};
        Q4 gc = {-gt_rot[k*4+0], -gt_rot[k*4+1], -gt_rot[k*4+2], gt_rot[k*4+3]};
        Q4 e = qmul(gc, rk);
        float n2 = e.x*e.x + e.y*e.y + e.z*e.z;
        float n = sqrtf(n2);
        float theta = 2.f*atan2f(n, e.w);
        float scale;
        if (n < 1e-6f) {
            float wd = (fabsf(e.w) < 1e-6f) ? 1.f : e.w;
            scale = 2.f/wd;
        } else {
            scale = theta/n;
        }
        out[k*3+0] = e.x*scale;
        out[k*3+1] = e.y*scale;
        out[k*3+2] = e.z*scale;

        float d0 = gt_pos[k*3+0] - spos[k][0];
        float d1 = gt_pos[k*3+1] - spos[k][1];
        float d2 = gt_pos[k*3+2] - spos[k][2];
        out[(NK+k)*3+0] = d0*d0;
        out[(NK+k)*3+1] = d1*d1;
        out[(NK+k)*3+2] = d2*d2;

        float v0 = gt_vel[k*3+0] - svel[k][0];
        float v1 = gt_vel[k*3+1] - svel[k][1];
        float v2 = gt_vel[k*3+2] - svel[k][2];
        out[(2*NK+k)*3+0] = v0*v0;
        out[(2*NK+k)*3+1] = v1*v1;
        out[(2*NK+k)*3+2] = v2*v2;
    }
}

extern "C" void kernel_launch(void* const* d_in, const int* in_sizes, int n_in,
                              void* d_out, int out_size, void* d_ws, size_t ws_size,
                              hipStream_t stream) {
    const float* acc      = (const float*)d_in[0];
    const float* gyro     = (const float*)d_in[1];
    const float* dt       = (const float*)d_in[2];
    const float* bias_a   = (const float*)d_in[3];
    const float* bias_w   = (const float*)d_in[4];
    const float* g        = (const float*)d_in[5];
    const float* init_rot = (const float*)d_in[6];
    const float* init_pos = (const float*)d_in[7];
    const float* init_vel = (const float*)d_in[8];
    const float* gt_rot   = (const float*)d_in[9];
    const float* gt_pos   = (const float*)d_in[10];
    const float* gt_vel   = (const float*)d_in[11];
    float* ws  = (float*)d_ws;
    float* out = (float*)d_out;

    imu_phase1<<<NM/4, 256, 0, stream>>>(acc, gyro, dt, bias_a, bias_w, ws);
    imu_phase2<<<1, 256, 0, stream>>>(ws, g, init_rot, init_pos, init_vel,
                                      gt_rot, gt_pos, gt_vel, out);
}

// Round 16
// 18.566 us; speedup vs baseline: 1.5642x; 1.0096x over previous
//
#include <hip/hip_runtime.h>
#include <math.h>

#define NM 1024
#define NS 256
#define NK 1025
#define CS 4    // steps per chunk
#define NC 64   // chunks per sequence = lanes per wave

struct Q4 { float x, y, z, w; };

__device__ __forceinline__ Q4 qmul(const Q4 a, const Q4 b) {
    Q4 o;
    o.x = a.w*b.x + a.x*b.w + a.y*b.z - a.z*b.y;
    o.y = a.w*b.y - a.x*b.z + a.y*b.w + a.z*b.x;
    o.z = a.w*b.z + a.x*b.y - a.y*b.x + a.z*b.w;
    o.w = a.w*b.w - a.x*b.x - a.y*b.y - a.z*b.z;
    return o;
}

__device__ __forceinline__ void q2m(const Q4 q, float* R) {
    float x = q.x, y = q.y, z = q.z, w = q.w;
    R[0] = 1.f - 2.f*(y*y + z*z); R[1] = 2.f*(x*y - z*w);       R[2] = 2.f*(x*z + y*w);
    R[3] = 2.f*(x*y + z*w);       R[4] = 1.f - 2.f*(x*x + z*z); R[5] = 2.f*(y*z - x*w);
    R[6] = 2.f*(x*z - y*w);       R[7] = 2.f*(y*z + x*w);       R[8] = 1.f - 2.f*(x*x + y*y);
}

__device__ __forceinline__ void m3mul(float* o, const float* X, const float* Y) {
    #pragma unroll
    for (int r = 0; r < 3; ++r)
        #pragma unroll
        for (int c = 0; c < 3; ++c)
            o[r*3+c] = X[r*3+0]*Y[c] + X[r*3+1]*Y[3+c] + X[r*3+2]*Y[6+c];
}

__device__ __forceinline__ void m3v(float* o, const float* X, const float* v) {
    o[0] = X[0]*v[0] + X[1]*v[1] + X[2]*v[2];
    o[1] = X[3]*v[0] + X[4]*v[1] + X[5]*v[2];
    o[2] = X[6]*v[0] + X[7]*v[1] + X[8]*v[2];
}

__device__ __forceinline__ void skmul(float* o, float x, float y, float z, const float* M) {
    #pragma unroll
    for (int c = 0; c < 3; ++c) {
        float m0 = M[c], m1 = M[3+c], m2 = M[6+c];
        o[c]   = -z*m1 + y*m2;
        o[3+c] =  z*m0 - x*m2;
        o[6+c] = -y*m0 + x*m1;
    }
}

__device__ __forceinline__ void crossv(float* o, float x, float y, float z, const float* v) {
    o[0] = -z*v[1] + y*v[2];
    o[1] =  z*v[0] - x*v[2];
    o[2] = -y*v[0] + x*v[1];
}

__device__ __forceinline__ void ld12(float* dst, const float4* src) {
    float4 t0 = src[0], t1 = src[1], t2 = src[2];
    dst[0]=t0.x; dst[1]=t0.y; dst[2] =t0.z; dst[3] =t0.w;
    dst[4]=t1.x; dst[5]=t1.y; dst[6] =t1.z; dst[7] =t1.w;
    dst[8]=t2.x; dst[9]=t2.y; dst[10]=t2.z; dst[11]=t2.w;
}

// ------------------------------------------------------------------
// Phase 1 (R13/R15-verified): wave per sequence, lane = chunk (CS=4),
// bias-contracted leaf fields + ONE fused 6-round scan (quat+T+affine)
// + 6-round butterfly. No LDS, no barriers.
// ------------------------------------------------------------------
__global__ __launch_bounds__(256, 2) void imu_phase1(
    const float* __restrict__ acc, const float* __restrict__ gyro,
    const float* __restrict__ dt, const float* __restrict__ bias_a,
    const float* __restrict__ bias_w, float* __restrict__ ws)
{
    const int lane = threadIdx.x & 63;
    const int m    = blockIdx.x * 4 + (threadIdx.x >> 6);
    const int c    = lane;

    float av[12], gv[12], bav[12], bwv[12], dtv[4];
    ld12(av,  (const float4*)(acc    + (size_t)m*NS*3) + c*3);
    ld12(gv,  (const float4*)(gyro   + (size_t)m*NS*3) + c*3);
    ld12(bav, (const float4*)(bias_a + (size_t)m*NS*3) + c*3);
    ld12(bwv, (const float4*)(bias_w + (size_t)m*NS*3) + c*3);
    {
        float4 t = ((const float4*)(dt + (size_t)m*NS))[c];
        dtv[0]=t.x; dtv[1]=t.y; dtv[2]=t.z; dtv[3]=t.w;
    }

    float ba0[3], bw0[3];
    ba0[0] = __shfl(bav[0], 0, 64); ba0[1] = __shfl(bav[1], 0, 64); ba0[2] = __shfl(bav[2], 0, 64);
    bw0[0] = __shfl(bwv[0], 0, 64); bw0[1] = __shfl(bwv[1], 0, 64); bw0[2] = __shfl(bwv[2], 0, 64);

    Q4 fq = {0.f, 0.f, 0.f, 1.f};
    float G[9] = {1.f,0.f,0.f, 0.f,1.f,0.f, 0.f,0.f,1.f};
    float T = 0.f;
    float u[3] = {0.f}, z[3] = {0.f};
    float A[9]  = {1.f,0.f,0.f, 0.f,1.f,0.f, 0.f,0.f,1.f};
    float Bmv[3] = {0.f};
    float M1v[3] = {0.f}, N[9] = {0.f}, nnv[3] = {0.f};
    float K1v[3] = {0.f}, K2a[9] = {0.f}, k2bv[3] = {0.f};

    #pragma unroll
    for (int j = 0; j < CS; ++j) {
        float d  = dtv[j];
        float ax = av[j*3+0], ay = av[j*3+1], az = av[j*3+2];
        float gx = gv[j*3+0], gy = gv[j*3+1], gz = gv[j*3+2];
        float abx = ax - bav[j*3+0], aby = ay - bav[j*3+1], abz = az - bav[j*3+2];
        float wbx = gx - bwv[j*3+0], wby = gy - bwv[j*3+1], wbz = gz - bwv[j*3+2];

        #pragma unroll
        for (int i = 0; i < 3; ++i) { K1v[i] += d*M1v[i]; k2bv[i] += d*nnv[i]; }
        #pragma unroll
        for (int i = 0; i < 9; ++i) K2a[i] += d*N[i];

        float ga0 = G[0]*ax + G[1]*ay + G[2]*az;
        float ga1 = G[3]*ax + G[4]*ay + G[5]*az;
        float ga2 = G[6]*ax + G[7]*ay + G[8]*az;
        float hd2 = 0.5f*d*d;
        z[0] += d*u[0] + hd2*ga0;
        z[1] += d*u[1] + hd2*ga1;
        z[2] += d*u[2] + hd2*ga2;
        u[0] += d*ga0; u[1] += d*ga1; u[2] += d*ga2;
        T += d;

        float phx = gx*d, phy = gy*d, phz = gz*d;
        float th2 = phx*phx + phy*phy + phz*phz;
        float k  = 0.5f - th2*(1.0f/48.0f);
        float ew = 1.0f - th2*0.125f;
        Q4 e = {phx*k, phy*k, phz*k, ew};
        fq = qmul(fq, e);
        q2m(fq, G);

        {
            float gb[3]; m3v(gb, G, ba0);
            M1v[0] += d*gb[0]; M1v[1] += d*gb[1]; M1v[2] += d*gb[2];
        }
        {
            float SA[9], GX[9];
            skmul(SA, abx, aby, abz, A);
            m3mul(GX, G, SA);
            #pragma unroll
            for (int i = 0; i < 9; ++i) N[i] += d*GX[i];
        }
        {
            float cb[3], gc[3];
            crossv(cb, abx, aby, abz, Bmv);
            m3v(gc, G, cb);
            nnv[0] += d*gc[0]; nnv[1] += d*gc[1]; nnv[2] += d*gc[2];
        }
        {
            float WA[9];
            skmul(WA, wbx, wby, wbz, A);
            #pragma unroll
            for (int i = 0; i < 9; ++i) A[i] -= d*WA[i];
        }
        {
            float cw[3];
            crossv(cw, wbx, wby, wbz, Bmv);
            Bmv[0] -= d*(cw[0] + bw0[0]);
            Bmv[1] -= d*(cw[1] + bw0[1]);
            Bmv[2] -= d*(cw[2] + bw0[2]);
        }
    }

    // fused scan: quat prefix (+T) and affine (A,b) prefix
    Q4 qi = fq;
    float Ti = T;
    float bvec[3] = {Bmv[0], Bmv[1], Bmv[2]};
    #pragma unroll
    for (int off = 1; off < 64; off <<= 1) {
        Q4 y;
        y.x = __shfl_up(qi.x, off, 64);
        y.y = __shfl_up(qi.y, off, 64);
        y.z = __shfl_up(qi.z, off, 64);
        y.w = __shfl_up(qi.w, off, 64);
        float yT = __shfl_up(Ti, off, 64);
        float yA[9], yb[3];
        #pragma unroll
        for (int i = 0; i < 9; ++i) yA[i] = __shfl_up(A[i], off, 64);
        yb[0] = __shfl_up(bvec[0], off, 64);
        yb[1] = __shfl_up(bvec[1], off, 64);
        yb[2] = __shfl_up(bvec[2], off, 64);
        if (lane >= off) {
            qi = qmul(y, qi);
            Ti += yT;
            float nA[9], nb[3];
            m3mul(nA, A, yA);
            m3v(nb, A, yb);
            #pragma unroll
            for (int i = 0; i < 9; ++i) A[i] = nA[i];
            bvec[0] = nb[0] + bvec[0];
            bvec[1] = nb[1] + bvec[1];
            bvec[2] = nb[2] + bvec[2];
        }
    }

    Q4 qf;
    qf.x = __shfl(qi.x, 63, 64);
    qf.y = __shfl(qi.y, 63, 64);
    qf.z = __shfl(qi.z, 63, 64);
    qf.w = __shfl(qi.w, 63, 64);
    Q4 qp;
    qp.x = __shfl_up(qi.x, 1, 64);
    qp.y = __shfl_up(qi.y, 1, 64);
    qp.z = __shfl_up(qi.z, 1, 64);
    qp.w = __shfl_up(qi.w, 1, 64);
    if (lane == 0) { qp.x = 0.f; qp.y = 0.f; qp.z = 0.f; qp.w = 1.f; }
    float R[9]; q2m(qp, R);

    float Tw = __shfl(Ti, 63, 64);
    float Tsuf = Tw - Ti;

    float Q2fv[3];
    Q2fv[0] = __shfl(bvec[0], 63, 64);
    Q2fv[1] = __shfl(bvec[1], 63, 64);
    Q2fv[2] = __shfl(bvec[2], 63, 64);
    float qv[3];
    qv[0] = __shfl_up(bvec[0], 1, 64);
    qv[1] = __shfl_up(bvec[1], 1, 64);
    qv[2] = __shfl_up(bvec[2], 1, 64);
    if (lane == 0) { qv[0] = 0.f; qv[1] = 0.f; qv[2] = 0.f; }

    float nq[3], kq[3];
    m3v(nq, N, qv);
    m3v(kq, K2a, qv);
    float t1[3] = { u[0] - M1v[0] - nq[0] - nnv[0],
                    u[1] - M1v[1] - nq[1] - nnv[1],
                    u[2] - M1v[2] - nq[2] - nnv[2] };
    float t2[3] = { z[0] - K1v[0] - kq[0] - k2bv[0],
                    z[1] - K1v[1] - kq[1] - k2bv[1],
                    z[2] - K1v[2] - kq[2] - k2bv[2] };
    float bc[3], ac[3];
    m3v(bc, R, t1);
    m3v(ac, R, t2);
    ac[0] += Tsuf*bc[0]; ac[1] += Tsuf*bc[1]; ac[2] += Tsuf*bc[2];

    #pragma unroll
    for (int off = 1; off < 64; off <<= 1) {
        #pragma unroll
        for (int i = 0; i < 3; ++i) {
            bc[i] += __shfl_xor(bc[i], off, 64);
            ac[i] += __shfl_xor(ac[i], off, 64);
        }
    }

    if (lane != 0) return;

    float dthx = 0.5f*Q2fv[0], dthy = 0.5f*Q2fv[1], dthz = 0.5f*Q2fv[2];
    Q4 dq = {dthx, dthy, dthz, 1.0f};
    Q4 gamma = qmul(qf, dq);

    float* g_gamma = ws;            // NM*4
    float* g_beta  = ws + 4*NM;     // NM*3
    float* g_alpha = ws + 7*NM;     // NM*3
    float* g_kf    = ws + 10*NM;    // NM
    ((float4*)g_gamma)[m] = make_float4(gamma.x, gamma.y, gamma.z, gamma.w);
    g_beta[m*3+0] = bc[0];  g_beta[m*3+1] = bc[1];  g_beta[m*3+2] = bc[2];
    g_alpha[m*3+0] = ac[0]; g_alpha[m*3+1] = ac[1]; g_alpha[m*3+2] = ac[2];
    g_kf[m] = Tw;
}

// ------------------------------------------------------------------
// Phase 2 (R15-verified 256-thread form) + epilogue-load prefetch:
// gt_rot/gt_pos/gt_vel are loaded into registers at kernel ENTRY so
// their HBM latency overlaps the scan phase (previously issued after
// 3 barriers with nothing to hide behind).
// ------------------------------------------------------------------
__global__ __launch_bounds__(256) void imu_phase2(
    const float* __restrict__ ws, const float* __restrict__ g,
    const float* __restrict__ init_rot, const float* __restrict__ init_pos,
    const float* __restrict__ init_vel, const float* __restrict__ gt_rot,
    const float* __restrict__ gt_pos, const float* __restrict__ gt_vel,
    float* __restrict__ out)
{
    __shared__ float4 srot[NK];
    __shared__ float  svel[NK][3];
    __shared__ float  spos[NK][3];
    __shared__ float4 qtot[4];
    __shared__ float  vtot[4][3];
    __shared__ float  ptot[4][3];

    const int tid  = threadIdx.x;   // 0..255
    const int lane = tid & 63;
    const int w    = tid >> 6;      // 0..3

    // ---- PREFETCH epilogue inputs (cold HBM) at entry ----
    float4 pr_rot[5];
    float  pr_pos[5][3], pr_vel[5][3];
    #pragma unroll
    for (int it = 0; it < 5; ++it) {
        int k = tid + it*256;
        if (k < NK) {
            pr_rot[it] = ((const float4*)gt_rot)[k];
            pr_pos[it][0] = gt_pos[k*3+0];
            pr_pos[it][1] = gt_pos[k*3+1];
            pr_pos[it][2] = gt_pos[k*3+2];
            pr_vel[it][0] = gt_vel[k*3+0];
            pr_vel[it][1] = gt_vel[k*3+1];
            pr_vel[it][2] = gt_vel[k*3+2];
        }
    }

    const float* g_gamma = ws;
    const float* g_beta  = ws + 4*NM;
    const float* g_alpha = ws + 7*NM;
    const float* g_kf    = ws + 10*NM;

    Q4 qinit = {init_rot[0], init_rot[1], init_rot[2], init_rot[3]};

    // ---- quat scan: local 4-compose + wave scan + cross-wave ----
    Q4 l0, l1, l2, l3;
    {
        const float4* gg = (const float4*)g_gamma;
        float4 a = gg[4*tid+0]; l0 = {a.x, a.y, a.z, a.w};
        float4 b = gg[4*tid+1]; l1 = qmul(l0, Q4{b.x, b.y, b.z, b.w});
        float4 cq = gg[4*tid+2]; l2 = qmul(l1, Q4{cq.x, cq.y, cq.z, cq.w});
        float4 dq = gg[4*tid+3]; l3 = qmul(l2, Q4{dq.x, dq.y, dq.z, dq.w});
    }
    Q4 inc = l3;
    #pragma unroll
    for (int off = 1; off < 64; off <<= 1) {
        Q4 y;
        y.x = __shfl_up(inc.x, off, 64);
        y.y = __shfl_up(inc.y, off, 64);
        y.z = __shfl_up(inc.z, off, 64);
        y.w = __shfl_up(inc.w, off, 64);
        if (lane >= off) inc = qmul(y, inc);
    }
    Q4 exc;
    exc.x = __shfl_up(inc.x, 1, 64);
    exc.y = __shfl_up(inc.y, 1, 64);
    exc.z = __shfl_up(inc.z, 1, 64);
    exc.w = __shfl_up(inc.w, 1, 64);
    if (lane == 0) { exc.x = 0.f; exc.y = 0.f; exc.z = 0.f; exc.w = 1.f; }
    if (lane == 63) qtot[w] = make_float4(inc.x, inc.y, inc.z, inc.w);
    __syncthreads();
    Q4 wpre = {0.f, 0.f, 0.f, 1.f};
    for (int j = 0; j < w; ++j) {
        float4 tq = qtot[j];
        wpre = qmul(wpre, Q4{tq.x, tq.y, tq.z, tq.w});
    }
    Q4 base = qmul(qmul(qinit, wpre), exc);   // rot at m = 4*tid (exclusive)
    Q4 r0 = base;
    Q4 r1 = qmul(base, l0);
    Q4 r2 = qmul(base, l1);
    Q4 r3 = qmul(base, l2);
    Q4 r4 = qmul(base, l3);
    srot[4*tid+1] = make_float4(r1.x, r1.y, r1.z, r1.w);
    srot[4*tid+2] = make_float4(r2.x, r2.y, r2.z, r2.w);
    srot[4*tid+3] = make_float4(r3.x, r3.y, r3.z, r3.w);
    srot[4*tid+4] = make_float4(r4.x, r4.y, r4.z, r4.w);
    if (tid == 0) srot[0] = make_float4(qinit.x, qinit.y, qinit.z, qinit.w);

    const float gx = g[0], gy = g[1], gz = g[2];
    const float iv0 = init_vel[0], iv1 = init_vel[1], iv2 = init_vel[2];
    const float ip0 = init_pos[0], ip1 = init_pos[1], ip2 = init_pos[2];

    float4 kf4 = ((const float4*)g_kf)[tid];
    float kf[4] = {kf4.x, kf4.y, kf4.z, kf4.w};
    float be[4][3], al[4][3];
    {
        const float4* gb = (const float4*)g_beta;
        float4 x0 = gb[3*tid+0], x1 = gb[3*tid+1], x2 = gb[3*tid+2];
        be[0][0]=x0.x; be[0][1]=x0.y; be[0][2]=x0.z;
        be[1][0]=x0.w; be[1][1]=x1.x; be[1][2]=x1.y;
        be[2][0]=x1.z; be[2][1]=x1.w; be[2][2]=x2.x;
        be[3][0]=x2.y; be[3][1]=x2.z; be[3][2]=x2.w;
        const float4* ga = (const float4*)g_alpha;
        float4 y0 = ga[3*tid+0], y1 = ga[3*tid+1], y2 = ga[3*tid+2];
        al[0][0]=y0.x; al[0][1]=y0.y; al[0][2]=y0.z;
        al[1][0]=y0.w; al[1][1]=y1.x; al[1][2]=y1.y;
        al[2][0]=y1.z; al[2][1]=y1.w; al[2][2]=y2.x;
        al[3][0]=y2.y; al[3][1]=y2.z; al[3][2]=y2.w;
    }
    Q4 rr[4] = {r0, r1, r2, r3};

    // ---- vel scan ----
    float dv[4][3], sv[4][3];
    #pragma unroll
    for (int i = 0; i < 4; ++i) {
        float Rw[9]; q2m(rr[i], Rw);
        dv[i][0] = -gx*kf[i] + Rw[0]*be[i][0] + Rw[1]*be[i][1] + Rw[2]*be[i][2];
        dv[i][1] = -gy*kf[i] + Rw[3]*be[i][0] + Rw[4]*be[i][1] + Rw[5]*be[i][2];
        dv[i][2] = -gz*kf[i] + Rw[6]*be[i][0] + Rw[7]*be[i][1] + Rw[8]*be[i][2];
        #pragma unroll
        for (int k = 0; k < 3; ++k)
            sv[i][k] = (i == 0) ? dv[0][k] : sv[i-1][k] + dv[i][k];
    }
    float a0s = sv[3][0], a1s = sv[3][1], a2s = sv[3][2];
    #pragma unroll
    for (int off = 1; off < 64; off <<= 1) {
        float y0 = __shfl_up(a0s, off, 64);
        float y1 = __shfl_up(a1s, off, 64);
        float y2 = __shfl_up(a2s, off, 64);
        if (lane >= off) { a0s += y0; a1s += y1; a2s += y2; }
    }
    float e0 = __shfl_up(a0s, 1, 64);
    float e1 = __shfl_up(a1s, 1, 64);
    float e2 = __shfl_up(a2s, 1, 64);
    if (lane == 0) { e0 = 0.f; e1 = 0.f; e2 = 0.f; }
    if (lane == 63) { vtot[w][0] = a0s; vtot[w][1] = a1s; vtot[w][2] = a2s; }
    __syncthreads();
    {
        float p0 = 0.f, p1 = 0.f, p2 = 0.f;
        for (int j = 0; j < w; ++j) { p0 += vtot[j][0]; p1 += vtot[j][1]; p2 += vtot[j][2]; }
        e0 += p0; e1 += p1; e2 += p2;
    }
    float velm[4][3];
    #pragma unroll
    for (int i = 0; i < 4; ++i) {
        velm[i][0] = iv0 + e0 + ((i == 0) ? 0.f : sv[i-1][0]);
        velm[i][1] = iv1 + e1 + ((i == 0) ? 0.f : sv[i-1][1]);
        velm[i][2] = iv2 + e2 + ((i == 0) ? 0.f : sv[i-1][2]);
        svel[4*tid+i+1][0] = iv0 + e0 + sv[i][0];
        svel[4*tid+i+1][1] = iv1 + e1 + sv[i][1];
        svel[4*tid+i+1][2] = iv2 + e2 + sv[i][2];
    }
    if (tid == 0) { svel[0][0] = iv0; svel[0][1] = iv1; svel[0][2] = iv2; }

    // ---- pos scan ----
    float dp[4][3], sp[4][3];
    #pragma unroll
    for (int i = 0; i < 4; ++i) {
        float Rw[9]; q2m(rr[i], Rw);
        float kk = kf[i], hk = 0.5f*kk*kk;
        dp[i][0] = velm[i][0]*kk - gx*hk + Rw[0]*al[i][0] + Rw[1]*al[i][1] + Rw[2]*al[i][2];
        dp[i][1] = velm[i][1]*kk - gy*hk + Rw[3]*al[i][0] + Rw[4]*al[i][1] + Rw[5]*al[i][2];
        dp[i][2] = velm[i][2]*kk - gz*hk + Rw[6]*al[i][0] + Rw[7]*al[i][1] + Rw[8]*al[i][2];
        #pragma unroll
        for (int k = 0; k < 3; ++k)
            sp[i][k] = (i == 0) ? dp[0][k] : sp[i-1][k] + dp[i][k];
    }
    float b0s = sp[3][0], b1s = sp[3][1], b2s = sp[3][2];
    #pragma unroll
    for (int off = 1; off < 64; off <<= 1) {
        float y0 = __shfl_up(b0s, off, 64);
        float y1 = __shfl_up(b1s, off, 64);
        float y2 = __shfl_up(b2s, off, 64);
        if (lane >= off) { b0s += y0; b1s += y1; b2s += y2; }
    }
    float f0 = __shfl_up(b0s, 1, 64);
    float f1 = __shfl_up(b1s, 1, 64);
    float f2 = __shfl_up(b2s, 1, 64);
    if (lane == 0) { f0 = 0.f; f1 = 0.f; f2 = 0.f; }
    if (lane == 63) { ptot[w][0] = b0s; ptot[w][1] = b1s; ptot[w][2] = b2s; }
    __syncthreads();
    {
        float p0 = 0.f, p1 = 0.f, p2 = 0.f;
        for (int j = 0; j < w; ++j) { p0 += ptot[j][0]; p1 += ptot[j][1]; p2 += ptot[j][2]; }
        f0 += p0; f1 += p1; f2 += p2;
    }
    #pragma unroll
    for (int i = 0; i < 4; ++i) {
        spos[4*tid+i+1][0] = ip0 + f0 + sp[i][0];
        spos[4*tid+i+1][1] = ip1 + f1 + sp[i][1];
        spos[4*tid+i+1][2] = ip2 + f2 + sp[i][2];
    }
    if (tid == 0) { spos[0][0] = ip0; spos[0][1] = ip1; spos[0][2] = ip2; }
    __syncthreads();

    // ---- epilogue over k in [0, NK) using prefetched gt_* ----
    #pragma unroll
    for (int it = 0; it < 5; ++it) {
        int k = tid + it*256;
        if (k >= NK) break;
        float4 rv = srot[k];
        Q4 rk = {rv.x, rv.y, rv.z, rv.w};
        float4 gr = pr_rot[it];
        Q4 gc = {-gr.x, -gr.y, -gr.z, gr.w};
        Q4 e = qmul(gc, rk);
        float n2 = e.x*e.x + e.y*e.y + e.z*e.z;
        float n = sqrtf(n2);
        float theta = 2.f*atan2f(n, e.w);
        float scale;
        if (n < 1e-6f) {
            float wd = (fabsf(e.w) < 1e-6f) ? 1.f : e.w;
            scale = 2.f/wd;
        } else {
            scale = theta/n;
        }
        out[k*3+0] = e.x*scale;
        out[k*3+1] = e.y*scale;
        out[k*3+2] = e.z*scale;

        float d0 = pr_pos[it][0] - spos[k][0];
        float d1 = pr_pos[it][1] - spos[k][1];
        float d2 = pr_pos[it][2] - spos[k][2];
        out[(NK+k)*3+0] = d0*d0;
        out[(NK+k)*3+1] = d1*d1;
        out[(NK+k)*3+2] = d2*d2;

        float v0 = pr_vel[it][0] - svel[k][0];
        float v1 = pr_vel[it][1] - svel[k][1];
        float v2 = pr_vel[it][2] - svel[k][2];
        out[(2*NK+k)*3+0] = v0*v0;
        out[(2*NK+k)*3+1] = v1*v1;
        out[(2*NK+k)*3+2] = v2*v2;
    }
}

extern "C" void kernel_launch(void* const* d_in, const int* in_sizes, int n_in,
                              void* d_out, int out_size, void* d_ws, size_t ws_size,
                              hipStream_t stream) {
    const float* acc      = (const float*)d_in[0];
    const float* gyro     = (const float*)d_in[1];
    const float* dt       = (const float*)d_in[2];
    const float* bias_a   = (const float*)d_in[3];
    const float* bias_w   = (const float*)d_in[4];
    const float* g        = (const float*)d_in[5];
    const float* init_rot = (const float*)d_in[6];
    const float* init_pos = (const float*)d_in[7];
    const float* init_vel = (const float*)d_in[8];
    const float* gt_rot   = (const float*)d_in[9];
    const float* gt_pos   = (const float*)d_in[10];
    const float* gt_vel   = (const float*)d_in[11];
    float* ws  = (float*)d_ws;
    float* out = (float*)d_out;

    imu_phase1<<<NM/4, 256, 0, stream>>>(acc, gyro, dt, bias_a, bias_w, ws);
    imu_phase2<<<1, 256, 0, stream>>>(ws, g, init_rot, init_pos, init_vel,
                                      gt_rot, gt_pos, gt_vel, out);
}